// Round 13
// baseline (55.245 us; speedup 1.0000x reference)
//
#include <hip/hip_runtime.h>

// PHOG: lap = dw3x3(x, laplacian); gx,gy = dw3x3(lap, sobel); mag/ang -> 9-bin
// hist over pyramid cells (1+4+16), L1-ish then L2 normalize.
//
// R13 = R12's recipe (upfront float2 loads, med3 binning w/ 1e35-prescaled
// constants, no inline asm, plain launch_bounds(256), XCD swizzle) at 16-tall
// tiles: 4w x 16t per thread (64 px). Block = 64 cols x 256 rows = one cell-
// column strip; wave w == exactly cell (w, strip) -> butterfly reduce only,
// lane0 writes the cell. NO LDS, NO barriers anywhere. Amortization: reduce
// 3.75->1.875 inst/px, lap redundancy 1.25->1.125, loads 0.625/px, setup /2.

#define H_IMG 256
#define W_IMG 256

// boundary constants prescaled by 1e35: S'=sin(b)*1e35, C'=cos(b)*1e35
#define BS0 1.7364817766693033e34f
#define BC0 9.84807753012208e34f
#define BS1 5.0e34f
#define BC1 8.660254037844387e34f
#define BS2 7.66044443118978e34f
#define BC2 6.427876096865393e34f
#define BS3 9.396926207859084e34f
#define BC3 3.420201433256687e34f

// interior lap row (no row mask)
__device__ __forceinline__ void lap_row6(float dst[6], const float u[8], const float m[8],
                                         const float d[8], float wm0, float wm5) {
#pragma unroll
  for (int c = 0; c < 6; ++c)
    dst[c] = (u[c + 1] + d[c + 1]) + fmaf(-4.f, m[c + 1], m[c] + m[c + 2]);
  dst[0] *= wm0;
  dst[5] *= wm5;
}

// edge lap row (row mask may be 0)
__device__ __forceinline__ void lap_row6_rm(float dst[6], const float u[8], const float m[8],
                                            const float d[8], float wm0, float wm5, float rowm) {
#pragma unroll
  for (int c = 0; c < 6; ++c) {
    float v = (u[c + 1] + d[c + 1]) + fmaf(-4.f, m[c + 1], m[c] + m[c + 2]);
    dst[c] = v * rowm;
  }
  dst[0] *= wm0;
  dst[5] *= wm5;
}

// gradient + med3 cumulative binning for one output row (4 px) from lap rows A,B,C
// acc[0..8]: sums of mag where ang >= b_i (monotone boundaries); acc[9]: total
__device__ __forceinline__ void out_row4(const float A[6], const float B[6], const float C[6],
                                         float acc[10]) {
  float cs[6], dd[6];
#pragma unroll
  for (int c = 0; c < 6; ++c) {
    cs[c] = A[c] + fmaf(2.f, B[c], C[c]);
    dd[c] = C[c] - A[c];
  }
#pragma unroll
  for (int c = 0; c < 4; ++c) {
    float gx = cs[c + 2] - cs[c];
    float gy = fmaf(2.f, dd[c + 1], dd[c] + dd[c + 2]);
    float mag = __builtin_amdgcn_sqrtf(fmaf(gx, gx, fmaf(gy, gy, 1e-8f)));
    unsigned sg = __float_as_uint(gy) & 0x80000000u;
    float fx = __uint_as_float(__float_as_uint(gx) ^ sg);  // sign(gy)*gx
    float fy = fabsf(gy);                                  // free src modifier
    float b0 = fx * BS0;
    float b1 = fx * BS1;
    float b2 = fx * BS2;
    float b3 = fx * BS3;
    acc[0] = fmaf(mag, __builtin_amdgcn_fmed3f(fmaf(fy, BC0, -b0), 0.f, 1.f), acc[0]);
    acc[1] = fmaf(mag, __builtin_amdgcn_fmed3f(fmaf(fy, BC1, -b1), 0.f, 1.f), acc[1]);
    acc[2] = fmaf(mag, __builtin_amdgcn_fmed3f(fmaf(fy, BC2, -b2), 0.f, 1.f), acc[2]);
    acc[3] = fmaf(mag, __builtin_amdgcn_fmed3f(fmaf(fy, BC3, -b3), 0.f, 1.f), acc[3]);
    acc[4] = fmaf(mag, __builtin_amdgcn_fmed3f(fx * -1e35f, 0.f, 1.f), acc[4]);
    acc[5] = fmaf(mag, __builtin_amdgcn_fmed3f(fmaf(fy, -BC3, -b3), 0.f, 1.f), acc[5]);
    acc[6] = fmaf(mag, __builtin_amdgcn_fmed3f(fmaf(fy, -BC2, -b2), 0.f, 1.f), acc[6]);
    acc[7] = fmaf(mag, __builtin_amdgcn_fmed3f(fmaf(fy, -BC1, -b1), 0.f, 1.f), acc[7]);
    acc[8] = fmaf(mag, __builtin_amdgcn_fmed3f(fmaf(fy, -BC0, -b0), 0.f, 1.f), acc[8]);
    acc[9] += mag;
  }
}

// one x row (8 floats, window cols gc0-2..gc0+5) from global, zero-filled OOB
__device__ __forceinline__ void load_grow(const float* __restrict__ xim, int gr, bool valid,
                                          int o0, int o1, int o2, int o3,
                                          float mlo, float mhi, float r[8]) {
  if (valid) {
    const float* p = xim + gr * W_IMG;
    float2 a = *reinterpret_cast<const float2*>(p + o0);
    float2 b = *reinterpret_cast<const float2*>(p + o1);
    float2 c = *reinterpret_cast<const float2*>(p + o2);
    float2 d = *reinterpret_cast<const float2*>(p + o3);
    r[0] = a.x * mlo; r[1] = a.y * mlo;
    r[2] = b.x;       r[3] = b.y;
    r[4] = c.x;       r[5] = c.y;
    r[6] = d.x * mhi; r[7] = d.y * mhi;
  } else {
#pragma unroll
    for (int i = 0; i < 8; ++i) r[i] = 0.f;
  }
}

__global__ __launch_bounds__(256) void phog_hist_kernel(const float* __restrict__ x,
                                                        float* __restrict__ hist2) {
  // XCD swizzle: each XCD gets 64 whole bc-images (4 strip-blocks each).
  const int f = blockIdx.y * 4 + blockIdx.x;    // 0..2047, HW xcd ~ f%8
  const int xcd = f & 7;
  const int idx = f >> 3;                       // 0..255 within xcd
  const int bc = xcd * 64 + (idx >> 2);
  const int strip = idx & 3;                    // cell col 0..3
  const int C0 = strip * 64;
  const int tid = threadIdx.x;
  const int tcol = tid & 15;    // 16 threads x 4 px = 64 cols
  const int trow = tid >> 4;    // 16 threads x 16 px = 256 rows

  const float* xim = x + (size_t)bc * (H_IMG * W_IMG);

  const int gr0 = 16 * trow;      // first output row
  const int gc0 = C0 + 4 * tcol;  // first output col
  const int bcol = gc0 - 2;       // window col 0 (global)

  // clamped float2 offsets + masks for the 2 edge float2s
  const int o0 = (bcol < 0) ? 0 : bcol;
  const int o1 = gc0;
  const int o2 = gc0 + 2;
  const int o3 = (gc0 + 4 > 254) ? 254 : (gc0 + 4);
  const float mlo = (bcol >= 0) ? 1.f : 0.f;        // x cols gc0-2,gc0-1
  const float mhi = (gc0 + 5 <= 255) ? 1.f : 0.f;   // x cols gc0+4,gc0+5

  const bool vlo = trow > 0;    // x rows gr0-2, gr0-1 valid?
  const bool vhi = trow < 15;   // x rows gr0+16, gr0+17 valid?
  const float rm_first = vlo ? 1.f : 0.f;  // lap row gr0-1
  const float rm_last = vhi ? 1.f : 0.f;   // lap row gr0+16
  const float wm0 = (gc0 >= 1) ? 1.f : 0.f;        // lap col gc0-1
  const float wm5 = (gc0 + 4 <= 255) ? 1.f : 0.f;  // lap col gc0+4

  // ---- load the ENTIRE 20-row window upfront (compiler sinks as needed)
  float w0[8], w1[8], w2[8], w3[8], w4[8], w5[8], w6[8], w7[8], w8[8], w9[8];
  float w10[8], w11[8], w12[8], w13[8], w14[8], w15[8], w16[8], w17[8], w18[8], w19[8];
  load_grow(xim, gr0 - 2, vlo, o0, o1, o2, o3, mlo, mhi, w0);
  load_grow(xim, gr0 - 1, vlo, o0, o1, o2, o3, mlo, mhi, w1);
  load_grow(xim, gr0 + 0, true, o0, o1, o2, o3, mlo, mhi, w2);
  load_grow(xim, gr0 + 1, true, o0, o1, o2, o3, mlo, mhi, w3);
  load_grow(xim, gr0 + 2, true, o0, o1, o2, o3, mlo, mhi, w4);
  load_grow(xim, gr0 + 3, true, o0, o1, o2, o3, mlo, mhi, w5);
  load_grow(xim, gr0 + 4, true, o0, o1, o2, o3, mlo, mhi, w6);
  load_grow(xim, gr0 + 5, true, o0, o1, o2, o3, mlo, mhi, w7);
  load_grow(xim, gr0 + 6, true, o0, o1, o2, o3, mlo, mhi, w8);
  load_grow(xim, gr0 + 7, true, o0, o1, o2, o3, mlo, mhi, w9);
  load_grow(xim, gr0 + 8, true, o0, o1, o2, o3, mlo, mhi, w10);
  load_grow(xim, gr0 + 9, true, o0, o1, o2, o3, mlo, mhi, w11);
  load_grow(xim, gr0 + 10, true, o0, o1, o2, o3, mlo, mhi, w12);
  load_grow(xim, gr0 + 11, true, o0, o1, o2, o3, mlo, mhi, w13);
  load_grow(xim, gr0 + 12, true, o0, o1, o2, o3, mlo, mhi, w14);
  load_grow(xim, gr0 + 13, true, o0, o1, o2, o3, mlo, mhi, w15);
  load_grow(xim, gr0 + 14, true, o0, o1, o2, o3, mlo, mhi, w16);
  load_grow(xim, gr0 + 15, true, o0, o1, o2, o3, mlo, mhi, w17);
  load_grow(xim, gr0 + 16, vhi, o0, o1, o2, o3, mlo, mhi, w18);
  load_grow(xim, gr0 + 17, vhi, o0, o1, o2, o3, mlo, mhi, w19);

  float acc[10];
#pragma unroll
  for (int k = 0; k < 10; ++k) acc[k] = 0.f;

  // ---- compute: 18 lap rows (rotating 4 buffers), 16 output rows
  float lA[6], lB[6], lC[6], lD[6];
  lap_row6_rm(lA, w0, w1, w2, wm0, wm5, rm_first);    // lap gr0-1
  lap_row6(lB, w1, w2, w3, wm0, wm5);                 // lap gr0
  lap_row6(lC, w2, w3, w4, wm0, wm5);                 // lap gr0+1
  out_row4(lA, lB, lC, acc);                          // out gr0
  lap_row6(lD, w3, w4, w5, wm0, wm5);                 // lap gr0+2
  out_row4(lB, lC, lD, acc);                          // out gr0+1
  lap_row6(lA, w4, w5, w6, wm0, wm5);                 // lap gr0+3
  out_row4(lC, lD, lA, acc);                          // out gr0+2
  lap_row6(lB, w5, w6, w7, wm0, wm5);                 // lap gr0+4
  out_row4(lD, lA, lB, acc);                          // out gr0+3
  lap_row6(lC, w6, w7, w8, wm0, wm5);                 // lap gr0+5
  out_row4(lA, lB, lC, acc);                          // out gr0+4
  lap_row6(lD, w7, w8, w9, wm0, wm5);                 // lap gr0+6
  out_row4(lB, lC, lD, acc);                          // out gr0+5
  lap_row6(lA, w8, w9, w10, wm0, wm5);                // lap gr0+7
  out_row4(lC, lD, lA, acc);                          // out gr0+6
  lap_row6(lB, w9, w10, w11, wm0, wm5);               // lap gr0+8
  out_row4(lD, lA, lB, acc);                          // out gr0+7
  lap_row6(lC, w10, w11, w12, wm0, wm5);              // lap gr0+9
  out_row4(lA, lB, lC, acc);                          // out gr0+8
  lap_row6(lD, w11, w12, w13, wm0, wm5);              // lap gr0+10
  out_row4(lB, lC, lD, acc);                          // out gr0+9
  lap_row6(lA, w12, w13, w14, wm0, wm5);              // lap gr0+11
  out_row4(lC, lD, lA, acc);                          // out gr0+10
  lap_row6(lB, w13, w14, w15, wm0, wm5);              // lap gr0+12
  out_row4(lD, lA, lB, acc);                          // out gr0+11
  lap_row6(lC, w14, w15, w16, wm0, wm5);              // lap gr0+13
  out_row4(lA, lB, lC, acc);                          // out gr0+12
  lap_row6(lD, w15, w16, w17, wm0, wm5);              // lap gr0+14
  out_row4(lB, lC, lD, acc);                          // out gr0+13
  lap_row6(lA, w16, w17, w18, wm0, wm5);              // lap gr0+15
  out_row4(lC, lD, lA, acc);                          // out gr0+14
  lap_row6_rm(lB, w17, w18, w19, wm0, wm5, rm_last);  // lap gr0+16
  out_row4(lD, lA, lB, acc);                          // out gr0+15

  // ---- reduce: wave == exactly one 64x64 cell. Butterfly, lane0 writes.
#pragma unroll
  for (int k = 0; k < 10; ++k) {
    float v = acc[k];
#pragma unroll
    for (int off = 32; off > 0; off >>= 1) v += __shfl_xor(v, off);
    acc[k] = v;
  }
  const int lane = tid & 63;
  const int w = tid >> 6;  // wave id == cell row
  if (lane == 0) {
    float* dst = &hist2[((bc * 16) + (w * 4 + strip)) * 9];
    dst[0] = (acc[9] - acc[0]) + acc[8];
#pragma unroll
    for (int k = 1; k < 9; ++k) dst[k] = acc[k - 1] - acc[k];
  }
}

__global__ __launch_bounds__(256) void phog_norm_kernel(const float* __restrict__ hist2,
                                                        float* __restrict__ out) {
  int t = blockIdx.x * 256 + threadIdx.x;
  if (t >= 32 * 336) return;
  int b = t / 336;
  int r = t - b * 336;

  float h[9];
  if (r < 16) {
    const float* p = hist2 + (b * 16 + r) * 144;
#pragma unroll
    for (int k = 0; k < 9; ++k) {
      float s = 0.f;
#pragma unroll
      for (int cell = 0; cell < 16; ++cell) s += p[cell * 9 + k];
      h[k] = s;
    }
  } else if (r < 80) {
    int q = r - 16;
    int c = q >> 2;
    int cell = q & 3;
    int r1 = cell >> 1, c1 = cell & 1;
    const float* p = hist2 + (b * 16 + c) * 144;
    int i00 = ((2 * r1) * 4 + 2 * c1) * 9;
    int i01 = ((2 * r1) * 4 + 2 * c1 + 1) * 9;
    int i10 = ((2 * r1 + 1) * 4 + 2 * c1) * 9;
    int i11 = ((2 * r1 + 1) * 4 + 2 * c1 + 1) * 9;
#pragma unroll
    for (int k = 0; k < 9; ++k) h[k] = (p[i00 + k] + p[i01 + k]) + (p[i10 + k] + p[i11 + k]);
  } else {
    int q = r - 80;
    int c = q >> 4;
    int cell = q & 15;
    const float* p = hist2 + ((b * 16 + c) * 16 + cell) * 9;
#pragma unroll
    for (int k = 0; k < 9; ++k) h[k] = p[k];
  }

  float s = 0.f;
#pragma unroll
  for (int k = 0; k < 9; ++k) s += h[k];
  float inv = 1.f / (s + 1e-8f);
#pragma unroll
  for (int k = 0; k < 9; ++k) h[k] *= inv;
  float n2 = 0.f;
#pragma unroll
  for (int k = 0; k < 9; ++k) n2 = fmaf(h[k], h[k], n2);
  float nrm = sqrtf(n2);
  float inv2 = 1.f / fmaxf(nrm, 1e-12f);
#pragma unroll
  for (int k = 0; k < 9; ++k) out[t * 9 + k] = h[k] * inv2;
}

extern "C" void kernel_launch(void* const* d_in, const int* in_sizes, int n_in,
                              void* d_out, int out_size, void* d_ws, size_t ws_size,
                              hipStream_t stream) {
  const float* x = (const float*)d_in[0];
  float* out = (float*)d_out;
  float* hist2 = (float*)d_ws;  // 512*16*9 floats = 294912 B

  dim3 g1(4, 512);
  phog_hist_kernel<<<g1, 256, 0, stream>>>(x, hist2);

  int total = 32 * 336;
  phog_norm_kernel<<<(total + 255) / 256, 256, 0, stream>>>(hist2, out);
}

// Round 14
// 52.824 us; speedup vs baseline: 1.0458x; 1.0458x over previous
//
#include <hip/hip_runtime.h>

// PHOG: lap = dw3x3(x, laplacian); gx,gy = dw3x3(lap, sobel); mag/ang -> 9-bin
// hist over pyramid cells (1+4+16), L1-ish then L2 normalize.
//
// R14 = revert to R12, the measured optimum of the family (52.9 us).
// Tile-height sweep: 16px/t=58.1, 32px/t=52.9, 64px/t=55.2 (VGPR 124,
// occupancy collapse). Recipe: upfront independent float2 loads (compiler
// sinks to balance MLP vs pressure), med3 binning with 1e35-prescaled
// boundary constants (saturates to exact 0/1), fx via sign-bit xor, |gy|
// free as source modifier, no inline asm (R9/R10: asm explodes the RA),
// plain launch_bounds(256) (R3/R4: min-occupancy hints force spill),
// XCD swizzle, interior lap rows skip row-mask mul.

#define H_IMG 256
#define W_IMG 256

// boundary constants prescaled by 1e35: S'=sin(b)*1e35, C'=cos(b)*1e35
#define BS0 1.7364817766693033e34f
#define BC0 9.84807753012208e34f
#define BS1 5.0e34f
#define BC1 8.660254037844387e34f
#define BS2 7.66044443118978e34f
#define BC2 6.427876096865393e34f
#define BS3 9.396926207859084e34f
#define BC3 3.420201433256687e34f

// interior lap row (no row mask)
__device__ __forceinline__ void lap_row6(float dst[6], const float u[8], const float m[8],
                                         const float d[8], float wm0, float wm5) {
#pragma unroll
  for (int c = 0; c < 6; ++c)
    dst[c] = (u[c + 1] + d[c + 1]) + fmaf(-4.f, m[c + 1], m[c] + m[c + 2]);
  dst[0] *= wm0;
  dst[5] *= wm5;
}

// edge lap row (row mask may be 0)
__device__ __forceinline__ void lap_row6_rm(float dst[6], const float u[8], const float m[8],
                                            const float d[8], float wm0, float wm5, float rowm) {
#pragma unroll
  for (int c = 0; c < 6; ++c) {
    float v = (u[c + 1] + d[c + 1]) + fmaf(-4.f, m[c + 1], m[c] + m[c + 2]);
    dst[c] = v * rowm;
  }
  dst[0] *= wm0;
  dst[5] *= wm5;
}

// gradient + med3 cumulative binning for one output row (4 px) from lap rows A,B,C
// acc[0..8]: sums of mag where ang >= b_i (monotone boundaries); acc[9]: total
__device__ __forceinline__ void out_row4(const float A[6], const float B[6], const float C[6],
                                         float acc[10]) {
  float cs[6], dd[6];
#pragma unroll
  for (int c = 0; c < 6; ++c) {
    cs[c] = A[c] + fmaf(2.f, B[c], C[c]);
    dd[c] = C[c] - A[c];
  }
#pragma unroll
  for (int c = 0; c < 4; ++c) {
    float gx = cs[c + 2] - cs[c];
    float gy = fmaf(2.f, dd[c + 1], dd[c] + dd[c + 2]);
    float mag = __builtin_amdgcn_sqrtf(fmaf(gx, gx, fmaf(gy, gy, 1e-8f)));
    unsigned sg = __float_as_uint(gy) & 0x80000000u;
    float fx = __uint_as_float(__float_as_uint(gx) ^ sg);  // sign(gy)*gx
    float fy = fabsf(gy);                                  // free src modifier
    float b0 = fx * BS0;
    float b1 = fx * BS1;
    float b2 = fx * BS2;
    float b3 = fx * BS3;
    acc[0] = fmaf(mag, __builtin_amdgcn_fmed3f(fmaf(fy, BC0, -b0), 0.f, 1.f), acc[0]);
    acc[1] = fmaf(mag, __builtin_amdgcn_fmed3f(fmaf(fy, BC1, -b1), 0.f, 1.f), acc[1]);
    acc[2] = fmaf(mag, __builtin_amdgcn_fmed3f(fmaf(fy, BC2, -b2), 0.f, 1.f), acc[2]);
    acc[3] = fmaf(mag, __builtin_amdgcn_fmed3f(fmaf(fy, BC3, -b3), 0.f, 1.f), acc[3]);
    acc[4] = fmaf(mag, __builtin_amdgcn_fmed3f(fx * -1e35f, 0.f, 1.f), acc[4]);
    acc[5] = fmaf(mag, __builtin_amdgcn_fmed3f(fmaf(fy, -BC3, -b3), 0.f, 1.f), acc[5]);
    acc[6] = fmaf(mag, __builtin_amdgcn_fmed3f(fmaf(fy, -BC2, -b2), 0.f, 1.f), acc[6]);
    acc[7] = fmaf(mag, __builtin_amdgcn_fmed3f(fmaf(fy, -BC1, -b1), 0.f, 1.f), acc[7]);
    acc[8] = fmaf(mag, __builtin_amdgcn_fmed3f(fmaf(fy, -BC0, -b0), 0.f, 1.f), acc[8]);
    acc[9] += mag;
  }
}

// one x row (8 floats, window cols gc0-2..gc0+5) from global, zero-filled OOB
__device__ __forceinline__ void load_grow(const float* __restrict__ xim, int gr, bool valid,
                                          int o0, int o1, int o2, int o3,
                                          float mlo, float mhi, float r[8]) {
  if (valid) {
    const float* p = xim + gr * W_IMG;
    float2 a = *reinterpret_cast<const float2*>(p + o0);
    float2 b = *reinterpret_cast<const float2*>(p + o1);
    float2 c = *reinterpret_cast<const float2*>(p + o2);
    float2 d = *reinterpret_cast<const float2*>(p + o3);
    r[0] = a.x * mlo; r[1] = a.y * mlo;
    r[2] = b.x;       r[3] = b.y;
    r[4] = c.x;       r[5] = c.y;
    r[6] = d.x * mhi; r[7] = d.y * mhi;
  } else {
#pragma unroll
    for (int i = 0; i < 8; ++i) r[i] = 0.f;
  }
}

__global__ __launch_bounds__(256) void phog_hist_kernel(const float* __restrict__ x,
                                                        float* __restrict__ hist2) {
  // XCD swizzle: give each XCD 64 whole bc-images (8 half-image blocks each).
  const int f = blockIdx.y * 8 + blockIdx.x;    // 0..4095, HW xcd ~ f%8
  const int xcd = f & 7;
  const int idx = f >> 3;                       // 0..511 within xcd
  const int bc = xcd * 64 + (idx >> 3);
  const int half = idx & 7;                     // 0..7: (tr2 = half>>2, tc = half&3)
  const int tr2 = half >> 2;
  const int tc = half & 3;
  const int R0 = tr2 * 128;     // block covers rows R0..R0+127 (2 cells)
  const int C0 = tc * 64;
  const int tid = threadIdx.x;
  const int tcol = tid & 15;    // 4 cols each
  const int trow = tid >> 4;    // 8 rows each

  const float* xim = x + (size_t)bc * (H_IMG * W_IMG);

  const int gr0 = R0 + 8 * trow;  // first output row
  const int gc0 = C0 + 4 * tcol;  // first output col
  const int bcol = gc0 - 2;       // window col 0 (global)

  // clamped float2 offsets + masks for the 2 edge float2s
  const int o0 = (bcol < 0) ? 0 : bcol;
  const int o1 = gc0;
  const int o2 = gc0 + 2;
  const int o3 = (gc0 + 4 > 254) ? 254 : (gc0 + 4);
  const float mlo = (bcol >= 0) ? 1.f : 0.f;        // x cols gc0-2,gc0-1
  const float mhi = (gc0 + 5 <= 255) ? 1.f : 0.f;   // x cols gc0+4,gc0+5

  const bool vlo = gr0 > 0;     // x rows gr0-2, gr0-1 valid?
  const bool vhi = gr0 < 248;   // x rows gr0+8, gr0+9 valid?
  const float rm_first = vlo ? 1.f : 0.f;  // lap row gr0-1
  const float rm_last = vhi ? 1.f : 0.f;   // lap row gr0+8
  const float wm0 = (gc0 >= 1) ? 1.f : 0.f;        // lap col gc0-1
  const float wm5 = (gc0 + 4 <= 255) ? 1.f : 0.f;  // lap col gc0+4

  // ---- load the ENTIRE 12-row window upfront: 48 independent float2 loads
  float w0[8], w1[8], w2[8], w3[8], w4[8], w5[8];
  float w6[8], w7[8], w8[8], w9[8], w10[8], w11[8];
  load_grow(xim, gr0 - 2, vlo, o0, o1, o2, o3, mlo, mhi, w0);
  load_grow(xim, gr0 - 1, vlo, o0, o1, o2, o3, mlo, mhi, w1);
  load_grow(xim, gr0 + 0, true, o0, o1, o2, o3, mlo, mhi, w2);
  load_grow(xim, gr0 + 1, true, o0, o1, o2, o3, mlo, mhi, w3);
  load_grow(xim, gr0 + 2, true, o0, o1, o2, o3, mlo, mhi, w4);
  load_grow(xim, gr0 + 3, true, o0, o1, o2, o3, mlo, mhi, w5);
  load_grow(xim, gr0 + 4, true, o0, o1, o2, o3, mlo, mhi, w6);
  load_grow(xim, gr0 + 5, true, o0, o1, o2, o3, mlo, mhi, w7);
  load_grow(xim, gr0 + 6, true, o0, o1, o2, o3, mlo, mhi, w8);
  load_grow(xim, gr0 + 7, true, o0, o1, o2, o3, mlo, mhi, w9);
  load_grow(xim, gr0 + 8, vhi, o0, o1, o2, o3, mlo, mhi, w10);
  load_grow(xim, gr0 + 9, vhi, o0, o1, o2, o3, mlo, mhi, w11);

  float acc[10];
#pragma unroll
  for (int k = 0; k < 10; ++k) acc[k] = 0.f;

  // ---- compute: 10 lap rows (rotating 4 buffers), 8 output rows
  float lA[6], lB[6], lC[6], lD[6];
  lap_row6_rm(lA, w0, w1, w2, wm0, wm5, rm_first);  // lap gr0-1
  lap_row6(lB, w1, w2, w3, wm0, wm5);               // lap gr0
  lap_row6(lC, w2, w3, w4, wm0, wm5);               // lap gr0+1
  out_row4(lA, lB, lC, acc);                        // out gr0
  lap_row6(lD, w3, w4, w5, wm0, wm5);               // lap gr0+2
  out_row4(lB, lC, lD, acc);                        // out gr0+1
  lap_row6(lA, w4, w5, w6, wm0, wm5);               // lap gr0+3
  out_row4(lC, lD, lA, acc);                        // out gr0+2
  lap_row6(lB, w5, w6, w7, wm0, wm5);               // lap gr0+4
  out_row4(lD, lA, lB, acc);                        // out gr0+3
  lap_row6(lC, w6, w7, w8, wm0, wm5);               // lap gr0+5
  out_row4(lA, lB, lC, acc);                        // out gr0+4
  lap_row6(lD, w7, w8, w9, wm0, wm5);               // lap gr0+6
  out_row4(lB, lC, lD, acc);                        // out gr0+5
  lap_row6(lA, w8, w9, w10, wm0, wm5);              // lap gr0+7
  out_row4(lC, lD, lA, acc);                        // out gr0+6
  lap_row6_rm(lB, w9, w10, w11, wm0, wm5, rm_last); // lap gr0+8
  out_row4(lD, lA, lB, acc);                        // out gr0+7

  // ---- reduce: wave butterfly (each wave lies within one cell), cross-wave LDS
#pragma unroll
  for (int k = 0; k < 10; ++k) {
    float v = acc[k];
#pragma unroll
    for (int off = 32; off > 0; off >>= 1) v += __shfl_xor(v, off);
    acc[k] = v;
  }

  __shared__ float hred[4][10];
  __shared__ float hs[2][10];
  const int lane = tid & 63;
  const int wave = tid >> 6;
  if (lane == 0) {
#pragma unroll
    for (int k = 0; k < 10; ++k) hred[wave][k] = acc[k];
  }
  __syncthreads();
  if (tid < 10) hs[0][tid] = hred[0][tid] + hred[1][tid];
  if (tid >= 32 && tid < 42) hs[1][tid - 32] = hred[2][tid - 32] + hred[3][tid - 32];
  __syncthreads();

  const int cell_top = (2 * tr2) * 4 + tc;
  const int cell_bot = (2 * tr2 + 1) * 4 + tc;
  if (tid < 9) {
    float h = (tid == 0) ? ((hs[0][9] - hs[0][0]) + hs[0][8]) : (hs[0][tid - 1] - hs[0][tid]);
    hist2[(bc * 16 + cell_top) * 9 + tid] = h;
  }
  if (tid >= 32 && tid < 41) {
    int k = tid - 32;
    float h = (k == 0) ? ((hs[1][9] - hs[1][0]) + hs[1][8]) : (hs[1][k - 1] - hs[1][k]);
    hist2[(bc * 16 + cell_bot) * 9 + k] = h;
  }
}

__global__ __launch_bounds__(256) void phog_norm_kernel(const float* __restrict__ hist2,
                                                        float* __restrict__ out) {
  int t = blockIdx.x * 256 + threadIdx.x;
  if (t >= 32 * 336) return;
  int b = t / 336;
  int r = t - b * 336;

  float h[9];
  if (r < 16) {
    const float* p = hist2 + (b * 16 + r) * 144;
#pragma unroll
    for (int k = 0; k < 9; ++k) {
      float s = 0.f;
#pragma unroll
      for (int cell = 0; cell < 16; ++cell) s += p[cell * 9 + k];
      h[k] = s;
    }
  } else if (r < 80) {
    int q = r - 16;
    int c = q >> 2;
    int cell = q & 3;
    int r1 = cell >> 1, c1 = cell & 1;
    const float* p = hist2 + (b * 16 + c) * 144;
    int i00 = ((2 * r1) * 4 + 2 * c1) * 9;
    int i01 = ((2 * r1) * 4 + 2 * c1 + 1) * 9;
    int i10 = ((2 * r1 + 1) * 4 + 2 * c1) * 9;
    int i11 = ((2 * r1 + 1) * 4 + 2 * c1 + 1) * 9;
#pragma unroll
    for (int k = 0; k < 9; ++k) h[k] = (p[i00 + k] + p[i01 + k]) + (p[i10 + k] + p[i11 + k]);
  } else {
    int q = r - 80;
    int c = q >> 4;
    int cell = q & 15;
    const float* p = hist2 + ((b * 16 + c) * 16 + cell) * 9;
#pragma unroll
    for (int k = 0; k < 9; ++k) h[k] = p[k];
  }

  float s = 0.f;
#pragma unroll
  for (int k = 0; k < 9; ++k) s += h[k];
  float inv = 1.f / (s + 1e-8f);
#pragma unroll
  for (int k = 0; k < 9; ++k) h[k] *= inv;
  float n2 = 0.f;
#pragma unroll
  for (int k = 0; k < 9; ++k) n2 = fmaf(h[k], h[k], n2);
  float nrm = sqrtf(n2);
  float inv2 = 1.f / fmaxf(nrm, 1e-12f);
#pragma unroll
  for (int k = 0; k < 9; ++k) out[t * 9 + k] = h[k] * inv2;
}

extern "C" void kernel_launch(void* const* d_in, const int* in_sizes, int n_in,
                              void* d_out, int out_size, void* d_ws, size_t ws_size,
                              hipStream_t stream) {
  const float* x = (const float*)d_in[0];
  float* out = (float*)d_out;
  float* hist2 = (float*)d_ws;  // 512*16*9 floats = 294912 B

  dim3 g1(8, 512);
  phog_hist_kernel<<<g1, 256, 0, stream>>>(x, hist2);

  int total = 32 * 336;
  phog_norm_kernel<<<(total + 255) / 256, 256, 0, stream>>>(hist2, out);
}